// Round 5
// baseline (22.717 us; speedup 1.0000x reference)
//
#include <hip/hip_runtime.h>
#include <math.h>

// LocalPODLoss: out = 0.5 * (1e-6 + sqrt(ss)); ss = triangular-weighted squares
// of 16-long sliding-window sums of D = new - old along rows and cols, per
// (b,c) 32x32 tile. Only scale s=1 contributes.
//
// Lessons: R2 fences = +51us (per-block L2 writeback). R3 same-address atomics
// = +22us (~11ns per serialized RMW x 2048). This round: HIERARCHICAL combine.
// One packed u64 atomicAdd per block ((q<<12)|1: fixed-point ss + arrival cnt)
// spread over 32 accumulators on separate 64B lines (max 64 RMW/address
// ~0.7us, parallel across channels). Group-last -> lvl2 counter (32 adds).
// Lvl2-last -> 32-lane parallel RMW-read + integer shuffle reduce (associative
// => bit-deterministic) -> sqrt -> store. No fences; ordering via same-address
// atomic serialization + asm data deps.

#define TILE_PAD 33
#define TILE_STRIDE (32 * TILE_PAD)      // 1056 floats per padded tile
#define NTILES 4                         // tiles per block
#define BLOCK_FLOATS (NTILES * 1024)     // 4096
#define NBLOCKS 2048
#define NGROUPS 32
#define GROUP_LAST 63ull                 // 2048/32 - 1
#define ACC_STRIDE 8                     // u64s per accumulator slot (64 B)
#define FP_SCALE 4096.0f                 // 2^12: ss*2^12 < 2^46 per group, fits 52-bit field

__global__ __launch_bounds__(256) void pod_fused(const float* __restrict__ nf,
                                                 const float* __restrict__ of,
                                                 unsigned long long* __restrict__ acc64,
                                                 unsigned* __restrict__ lvl2,
                                                 float* __restrict__ out) {
    __shared__ float ds[NTILES * TILE_STRIDE];   // 16.9 KB -> 8 blocks/CU
    __shared__ float wsum[4];
    __shared__ int sh_last;
    const int tid = threadIdx.x;
    if (tid == 0) sh_last = 0;

    const size_t base = (size_t)blockIdx.x * BLOCK_FLOATS;
    const float4* nf4 = reinterpret_cast<const float4*>(nf + base);
    const float4* of4 = reinterpret_cast<const float4*>(of + base);

    // ---- all loads issued upfront (max MLP), then subtract+stage ----
    float4 a[NTILES], b[NTILES];
#pragma unroll
    for (int it = 0; it < NTILES; ++it) a[it] = nf4[it * 256 + tid];
#pragma unroll
    for (int it = 0; it < NTILES; ++it) b[it] = of4[it * 256 + tid];

#pragma unroll
    for (int it = 0; it < NTILES; ++it) {
        int e = (it * 256 + tid) * 4;            // flat float index (32%4==0: no row crossing)
        int tile = e >> 10, r = (e >> 5) & 31, c = e & 31;
        float* dst = &ds[tile * TILE_STRIDE + r * TILE_PAD + c];
        dst[0] = a[it].x - b[it].x;
        dst[1] = a[it].y - b[it].y;
        dst[2] = a[it].z - b[it].z;
        dst[3] = a[it].w - b[it].w;
    }
    __syncthreads();

    // ---- waves 0-1: 'left' term (column windows, stride-33, conflict-free);
    //      waves 2-3: 'right' term (row windows). Wave-uniform branch. ----
    const int item = tid & 127;
    const int tile = item >> 5;
    const int lane = item & 31;
    float v[32];
    if (tid < 128) {
        const float* p = &ds[tile * TILE_STRIDE + lane];
#pragma unroll
        for (int k = 0; k < 32; ++k) v[k] = p[k * TILE_PAD];
    } else {
        const float* p = &ds[tile * TILE_STRIDE + lane * TILE_PAD];
#pragma unroll
        for (int k = 0; k < 32; ++k) v[k] = p[k];
    }
    float W = 0.0f;
#pragma unroll
    for (int k = 0; k < 16; ++k) W += v[k];
    float s2 = W * W;
#pragma unroll
    for (int i = 1; i < 16; ++i) { W += v[i + 15] - v[i - 1]; s2 += W * W; }
    float wgt = (lane < 16) ? (float)(lane + 1) : (float)(31 - lane);  // triangular cnt
    float acc = wgt * s2 * (1.0f / 256.0f);      // the /w and /h squared

    // ---- deterministic block reduction: wave64 shuffle + LDS combine ----
#pragma unroll
    for (int off = 32; off > 0; off >>= 1) acc += __shfl_down(acc, off, 64);
    if ((tid & 63) == 0) wsum[tid >> 6] = acc;
    __syncthreads();

    if (tid == 0) {
        float total = (wsum[0] + wsum[1]) + (wsum[2] + wsum[3]);   // >= 0
        unsigned long long q = (unsigned long long)(total * FP_SCALE);
        const int grp = blockIdx.x & (NGROUPS - 1);   // temporal neighbors -> different lines
        unsigned long long old = atomicAdd(&acc64[grp * ACC_STRIDE], (q << 12) | 1ull);
        if ((old & 0xFFFull) == GROUP_LAST) {
            // group complete (same-address serialization). Dep-chain to lvl2.
            unsigned inc = 1u;
            asm volatile("" : "+v"(inc) : "v"((unsigned)old));
            unsigned l2 = atomicAdd(lvl2, inc);
            if (l2 == NGROUPS - 1u) sh_last = 1;      // all groups complete
        }
    }
    __syncthreads();

    if (sh_last && tid < 64) {
        long long myv = 0;
        if (tid < NGROUPS) {
            // parallel coherent read: one RMW-0 per lane, 32 lanes at once
            unsigned long long vraw = atomicAdd(&acc64[tid * ACC_STRIDE], 0ull);
            myv = (long long)((vraw - (GROUP_LAST + 1ull)) >> 12);  // strip count field
        }
#pragma unroll
        for (int off = 32; off > 0; off >>= 1) myv += __shfl_down(myv, off, 64);
        if (tid == 0) {
            double ss = (double)myv * (1.0 / (double)FP_SCALE);
            out[0] = 0.5f * (1e-6f + sqrtf((float)ss));
        }
    }
}

extern "C" void kernel_launch(void* const* d_in, const int* in_sizes, int n_in,
                              void* d_out, int out_size, void* d_ws, size_t ws_size,
                              hipStream_t stream) {
    const float* nf = (const float*)d_in[0];
    const float* of = (const float*)d_in[1];
    float* out = (float*)d_out;

    unsigned long long* acc64 = (unsigned long long*)d_ws;        // 32 slots x 64 B
    unsigned* lvl2 = (unsigned*)((char*)d_ws + NGROUPS * ACC_STRIDE * 8);

    hipMemsetAsync(d_ws, 0, 4096, stream);
    hipLaunchKernelGGL(pod_fused, dim3(NBLOCKS), dim3(256), 0, stream,
                       nf, of, acc64, lvl2, out);
}

// Round 6
// 17.680 us; speedup vs baseline: 1.2849x; 1.2849x over previous
//
#include <hip/hip_runtime.h>
#include <math.h>

// LocalPODLoss: out = 0.5 * (1e-6 + sqrt(ss)); ss = triangular-weighted squares
// of 16-long sliding-window sums of D = new - old along rows and cols, per
// (b,c) 32x32 tile. Only scale s=1 contributes (s=0 has zero window positions).
//
// Structure lessons: R2 fences +51us; R3 same-address atomics +22us; R5
// hierarchical atomics + memset node +5us (the memset NODE costs ~5us).
// => two plain kernels, no atomics/fences/memsets, fixed-order reductions
// (bit-deterministic). This round: pipeline kernel1 (grid 4096 x 128thr =
// 2 waves/block: later blocks' loads overlap earlier blocks' compute) and
// shrink kernel2 to a single barrier-free wave.

#define TILE_PAD 33
#define TILE_STRIDE (32 * TILE_PAD)      // 1056 floats per padded tile
#define NTILES 2                         // tiles per block
#define BLOCK_FLOATS (NTILES * 1024)     // 2048
#define NBLOCKS 4096                     // 8192 tiles / 2

__global__ __launch_bounds__(128) void pod_partial(const float* __restrict__ nf,
                                                   const float* __restrict__ of,
                                                   float* __restrict__ partial) {
    __shared__ float ds[NTILES * TILE_STRIDE];   // 8.4 KB
    const int tid = threadIdx.x;
    const size_t base = (size_t)blockIdx.x * BLOCK_FLOATS;
    const float4* nf4 = reinterpret_cast<const float4*>(nf + base);
    const float4* of4 = reinterpret_cast<const float4*>(of + base);

    // ---- all 8 loads issued upfront (max MLP), a/b interleaved ----
    float4 a[4], b[4];
#pragma unroll
    for (int it = 0; it < 4; ++it) {
        a[it] = nf4[it * 128 + tid];
        b[it] = of4[it * 128 + tid];
    }

    // ---- stage D = a - b into padded LDS tiles ----
#pragma unroll
    for (int it = 0; it < 4; ++it) {
        int e = (it * 128 + tid) * 4;            // flat float index (32%4==0: no row crossing)
        int tile = e >> 10, r = (e >> 5) & 31, c = e & 31;
        float* dst = &ds[tile * TILE_STRIDE + r * TILE_PAD + c];
        dst[0] = a[it].x - b[it].x;
        dst[1] = a[it].y - b[it].y;
        dst[2] = a[it].z - b[it].z;
        dst[3] = a[it].w - b[it].w;
    }
    __syncthreads();

    // ---- wave 0: 'left' term (column windows, stride-33 = conflict-free);
    //      wave 1: 'right' term (row windows). Wave-uniform branch.
    //      2 tiles x 32 lanes = 64 items per term. ----
    const int item = tid & 63;
    const int tile = item >> 5;
    const int lane = item & 31;
    float v[32];
    if (tid < 64) {
        const float* p = &ds[tile * TILE_STRIDE + lane];
#pragma unroll
        for (int k = 0; k < 32; ++k) v[k] = p[k * TILE_PAD];
    } else {
        const float* p = &ds[tile * TILE_STRIDE + lane * TILE_PAD];
#pragma unroll
        for (int k = 0; k < 32; ++k) v[k] = p[k];
    }
    float W = 0.0f;
#pragma unroll
    for (int k = 0; k < 16; ++k) W += v[k];
    float s2 = W * W;
#pragma unroll
    for (int i = 1; i < 16; ++i) { W += v[i + 15] - v[i - 1]; s2 += W * W; }
    float wgt = (lane < 16) ? (float)(lane + 1) : (float)(31 - lane);  // triangular cnt
    float acc = wgt * s2 * (1.0f / 256.0f);      // the /w and /h squared

    // ---- deterministic block reduction: wave64 shuffle + LDS combine ----
#pragma unroll
    for (int off = 32; off > 0; off >>= 1) acc += __shfl_down(acc, off, 64);
    __shared__ float wsum[2];
    if ((tid & 63) == 0) wsum[tid >> 6] = acc;
    __syncthreads();
    if (tid == 0) partial[blockIdx.x] = wsum[0] + wsum[1];
}

// Single wave, no LDS, no barriers: 16 float4 loads/lane (all in flight),
// fixed-order in-register sum + shuffle tree => bit-deterministic.
__global__ __launch_bounds__(64) void pod_final(const float* __restrict__ partial,
                                                float* __restrict__ out) {
    const int lane = threadIdx.x;
    const float4* p4 = reinterpret_cast<const float4*>(partial);
    float4 r[16];
#pragma unroll
    for (int i = 0; i < 16; ++i) r[i] = p4[i * 64 + lane];   // 1024 float4 total
    float s = 0.0f;
#pragma unroll
    for (int i = 0; i < 16; ++i) s += (r[i].x + r[i].y) + (r[i].z + r[i].w);
#pragma unroll
    for (int off = 32; off > 0; off >>= 1) s += __shfl_down(s, off, 64);
    if (lane == 0) out[0] = 0.5f * (1e-6f + sqrtf(s));
}

extern "C" void kernel_launch(void* const* d_in, const int* in_sizes, int n_in,
                              void* d_out, int out_size, void* d_ws, size_t ws_size,
                              hipStream_t stream) {
    const float* nf = (const float*)d_in[0];
    const float* of = (const float*)d_in[1];
    float* out = (float*)d_out;
    float* partial = (float*)d_ws;               // 4096 floats = 16 KB

    hipLaunchKernelGGL(pod_partial, dim3(NBLOCKS), dim3(128), 0, stream, nf, of, partial);
    hipLaunchKernelGGL(pod_final, dim3(1), dim3(64), 0, stream, partial, out);
}

// Round 8
// 15.075 us; speedup vs baseline: 1.5069x; 1.1728x over previous
//
#include <hip/hip_runtime.h>
#include <math.h>

// LocalPODLoss: out = 0.5 * (1e-6 + sqrt(ss)); ss = triangular-weighted squares
// of 16-long sliding-window sums of D = new - old along rows and cols, per
// (b,c) 32x32 tile. Only scale s=1 contributes (s=0 has zero window positions).
//
// Structure lessons: R2 fences +51us; R3 same-address atomics +22us; R5
// hierarchical atomics + memset node +5us. Two plain kernels, fixed-order
// reductions (bit-deterministic), no atomics/fences/memsets. R6: smaller
// blocks neutral -> R4 shape (2048 x 256, NTILES=4). This round: NT loads
// via native ext_vector_type (builtin rejects HIP_vector_type structs).

#define TILE_PAD 33
#define TILE_STRIDE (32 * TILE_PAD)      // 1056 floats per padded tile
#define NTILES 4                         // tiles per block
#define BLOCK_FLOATS (NTILES * 1024)     // 4096
#define NBLOCKS 2048

typedef float vf4 __attribute__((ext_vector_type(4)));

__global__ __launch_bounds__(256) void pod_partial(const float* __restrict__ nf,
                                                   const float* __restrict__ of,
                                                   float* __restrict__ partial) {
    __shared__ float ds[NTILES * TILE_STRIDE];   // 16.9 KB -> 8 blocks/CU
    const int tid = threadIdx.x;
    const size_t base = (size_t)blockIdx.x * BLOCK_FLOATS;
    const vf4* nf4 = reinterpret_cast<const vf4*>(nf + base);
    const vf4* of4 = reinterpret_cast<const vf4*>(of + base);

    // ---- all 8 loads issued upfront (max MLP), non-temporal (single pass) ----
    vf4 a[NTILES], b[NTILES];
#pragma unroll
    for (int it = 0; it < NTILES; ++it) a[it] = __builtin_nontemporal_load(&nf4[it * 256 + tid]);
#pragma unroll
    for (int it = 0; it < NTILES; ++it) b[it] = __builtin_nontemporal_load(&of4[it * 256 + tid]);

    // ---- stage D = a - b into padded LDS tiles ----
#pragma unroll
    for (int it = 0; it < NTILES; ++it) {
        int e = (it * 256 + tid) * 4;            // flat float index (32%4==0: no row crossing)
        int tile = e >> 10, r = (e >> 5) & 31, c = e & 31;
        float* dst = &ds[tile * TILE_STRIDE + r * TILE_PAD + c];
        vf4 d = a[it] - b[it];
        dst[0] = d.x;
        dst[1] = d.y;
        dst[2] = d.z;
        dst[3] = d.w;
    }
    __syncthreads();

    // ---- waves 0-1: 'left' term (column windows, stride-33 = conflict-free);
    //      waves 2-3: 'right' term (row windows). Wave-uniform branch.
    //      4 tiles x 32 lanes = 128 items per term. ----
    const int item = tid & 127;
    const int tile = item >> 5;
    const int lane = item & 31;
    float v[32];
    if (tid < 128) {
        const float* p = &ds[tile * TILE_STRIDE + lane];
#pragma unroll
        for (int k = 0; k < 32; ++k) v[k] = p[k * TILE_PAD];
    } else {
        const float* p = &ds[tile * TILE_STRIDE + lane * TILE_PAD];
#pragma unroll
        for (int k = 0; k < 32; ++k) v[k] = p[k];
    }
    float W = 0.0f;
#pragma unroll
    for (int k = 0; k < 16; ++k) W += v[k];
    float s2 = W * W;
#pragma unroll
    for (int i = 1; i < 16; ++i) { W += v[i + 15] - v[i - 1]; s2 += W * W; }
    float wgt = (lane < 16) ? (float)(lane + 1) : (float)(31 - lane);  // triangular cnt
    float acc = wgt * s2 * (1.0f / 256.0f);      // the /w and /h squared

    // ---- deterministic block reduction: wave64 shuffle + LDS combine ----
#pragma unroll
    for (int off = 32; off > 0; off >>= 1) acc += __shfl_down(acc, off, 64);
    __shared__ float wsum[4];
    if ((tid & 63) == 0) wsum[tid >> 6] = acc;
    __syncthreads();
    if (tid == 0) partial[blockIdx.x] = (wsum[0] + wsum[1]) + (wsum[2] + wsum[3]);
}

// Single wave, no LDS, no barriers: 8 float4 loads/lane all in flight, one
// waitcnt, fixed-order in-register sum + shuffle tree => bit-deterministic.
__global__ __launch_bounds__(64) void pod_final(const float* __restrict__ partial,
                                                float* __restrict__ out) {
    const int lane = threadIdx.x;
    const vf4* p4 = reinterpret_cast<const vf4*>(partial);
    vf4 r[8];
#pragma unroll
    for (int i = 0; i < 8; ++i) r[i] = __builtin_nontemporal_load(&p4[i * 64 + lane]);
    float s = 0.0f;
#pragma unroll
    for (int i = 0; i < 8; ++i) s += (r[i].x + r[i].y) + (r[i].z + r[i].w);
#pragma unroll
    for (int off = 32; off > 0; off >>= 1) s += __shfl_down(s, off, 64);
    if (lane == 0) out[0] = 0.5f * (1e-6f + sqrtf(s));
}

extern "C" void kernel_launch(void* const* d_in, const int* in_sizes, int n_in,
                              void* d_out, int out_size, void* d_ws, size_t ws_size,
                              hipStream_t stream) {
    const float* nf = (const float*)d_in[0];
    const float* of = (const float*)d_in[1];
    float* out = (float*)d_out;
    float* partial = (float*)d_ws;               // 2048 floats = 8 KB

    hipLaunchKernelGGL(pod_partial, dim3(NBLOCKS), dim3(256), 0, stream, nf, of, partial);
    hipLaunchKernelGGL(pod_final, dim3(1), dim3(64), 0, stream, partial, out);
}